// Round 9
// baseline (285.795 us; speedup 1.0000x reference)
//
#include <hip/hip_runtime.h>
#include <math.h>

#define BB 4
#define SS 4096
#define DD 128
#define NSPK 9
#define WIN 15
#define EPSN 1e-8f
#define INV_PI 0.31830988618379067f

typedef float vfloat4 __attribute__((ext_vector_type(4)));

// ---------------------------------------------------------------------------
// k_main: WAVE ROLE-SPLIT (R8) with PLAIN stores (R9 experiment: NT stores
// measured ~4.3 TB/s effective; rocclr fills with regular L2 stores hit
// ~6.4 TB/s — test that delta).
//   wid even -> FILL: plain zero-stores of BOTH FULL rows (no band-skip,
//     branch-free; k_bw overwrites the band span later). Row A then row B.
//   wid odd  -> COMPUTE: predicated band compute for the same two rows
//     (32 lanes per row), writes band[] and dinv[] only.
// ---------------------------------------------------------------------------
__global__ __launch_bounds__(256) void k_main(const float* __restrict__ x,
                                              const float* __restrict__ qmask,
                                              const int* __restrict__ dia_len,
                                              float* __restrict__ band,
                                              float* __restrict__ dinv,
                                              float* __restrict__ out) {
    int wid  = (blockIdx.x * blockDim.x + threadIdx.x) >> 6;   // 0..16383
    int lane = threadIdx.x & 63;
    int p    = wid >> 1;
    int rA = p * 2, rB = rA + 1;

    if (!(wid & 1)) {
        // ---------------- FILL role: store-only wave, branch-free ----------
        vfloat4 z = (vfloat4)(0.f);
        vfloat4* oA = (vfloat4*)(out + (size_t)rA * SS);
        vfloat4* oB = (vfloat4*)(out + (size_t)rB * SS);
        #pragma unroll
        for (int it = 0; it < SS / 4 / 64; ++it)     // row A: 16 KB
            oA[it * 64 + lane] = z;
        #pragma unroll
        for (int it = 0; it < SS / 4 / 64; ++it)     // row B: 16 KB
            oB[it * 64 + lane] = z;
        return;
    }

    // ---------------- COMPUTE role: load/VALU-only wave ----------------
    int half = lane >> 5;          // 0: row A, 1: row B
    int hl   = lane & 31;
    int row  = rA + half;
    int b    = row >> 12;
    int i    = row & (SS - 1);
    int len  = dia_len[b];

    int  j     = i - WIN + hl;                       // hl==31 -> out of band
    bool inr   = (hl < 31) && (j >= 0) && (j < SS);
    bool maskv = inr && (i < len) && (j < len);

    int sj = 0;
    if (inr) {
        const float* q = qmask + ((size_t)j * BB + b) * NSPK;
        float best = q[0];
        #pragma unroll
        for (int k = 1; k < NSPK; ++k) {
            float qv = q[k];
            if (qv > best) { best = qv; sj = k; }    // first-max tie-break
        }
    }
    int si = __shfl(sj, (lane & 32) + WIN);          // lane where j == i
    bool same = inr && (sj == si);

    float dot = 0.f, nj2 = 0.f;
    if (maskv) {
        const float4* xi = (const float4*)(x + (size_t)row * DD);
        const float4* xj = (const float4*)(x + ((size_t)(b << 12) + j) * DD);
        float d0 = 0.f, d1 = 0.f, n0 = 0.f, n1 = 0.f;
        #pragma unroll
        for (int d = 0; d < DD / 8; ++d) {
            float4 a0 = xi[2 * d],     c0 = xj[2 * d];
            float4 a1 = xi[2 * d + 1], c1 = xj[2 * d + 1];
            d0 += a0.x * c0.x + a0.y * c0.y + a0.z * c0.z + a0.w * c0.w;
            d1 += a1.x * c1.x + a1.y * c1.y + a1.z * c1.z + a1.w * c1.w;
            n0 += c0.x * c0.x + c0.y * c0.y + c0.z * c0.z + c0.w * c0.w;
            n1 += c1.x * c1.x + c1.y * c1.y + c1.z * c1.z + c1.w * c1.w;
        }
        dot = d0 + d1;
        nj2 = n0 + n1;
    }
    float ni2 = __shfl(nj2, (lane & 32) + WIN);      // ||x_i||^2 from j==i lane

    float aij = 0.f;
    if (maskv) {
        float ni = fmaxf(sqrtf(ni2), EPSN);
        float nj = fmaxf(sqrtf(nj2), EPSN);
        float c  = dot / (ni * nj);
        c = fminf(fmaxf(c, -1.f), 1.f);
        aij = 1.f - acosf(c) * INV_PI;
    }

    unsigned long long bal = __ballot(maskv && same);
    unsigned long long hm  = half ? 0xFFFFFFFF00000000ull
                                  : 0x00000000FFFFFFFFull;
    int cnt = __popcll(bal & hm);
    if (maskv && same && cnt > 1) aij *= 2.f;

    float deg = aij;
    #pragma unroll
    for (int off = 16; off; off >>= 1) deg += __shfl_xor(deg, off);

    band[(size_t)row * 32 + hl] = aij;               // hl==31 writes 0
    if (hl == 0) {
        float dv = (deg == 0.f) ? 1.f : deg;
        dinv[row] = 1.0f / sqrtf(dv);
    }
}

// ---------------------------------------------------------------------------
// k_bw: one wave per row; overwrites the float4-aligned band span with final
// values scaled by dinv_i * dinv_j (zeros at masked positions). ~2.4 MB.
// ---------------------------------------------------------------------------
__global__ __launch_bounds__(256) void k_bw(const float* __restrict__ band,
                                            const float* __restrict__ dinv,
                                            float* __restrict__ out) {
    int row  = (blockIdx.x * blockDim.x + threadIdx.x) >> 6;
    int lane = threadIdx.x & 63;
    if (row >= BB * SS) return;
    int b = row >> 12, i = row & (SS - 1);
    int j0 = i - WIN; if (j0 < 0) j0 = 0;
    int j1 = i + WIN; if (j1 > SS - 1) j1 = SS - 1;
    int fs = j0 >> 2, fe = j1 >> 2;

    int j = fs * 4 + lane;                           // covers [fs*4, fe*4+3]
    if (j > fe * 4 + 3) return;

    float v = 0.f;
    if (j >= j0 && j <= j1) {
        v = band[(size_t)row * 32 + (j - i + WIN)] * dinv[row] * dinv[b * SS + j];
    }
    out[(size_t)row * SS + j] = v;
}

extern "C" void kernel_launch(void* const* d_in, const int* in_sizes, int n_in,
                              void* d_out, int out_size, void* d_ws, size_t ws_size,
                              hipStream_t stream) {
    const float* x       = (const float*)d_in[0];
    const float* qmask   = (const float*)d_in[1];
    const int*   dia_len = (const int*)d_in[2];
    float* out = (float*)d_out;

    char* ws = (char*)d_ws;
    const size_t rows = (size_t)BB * SS;
    float* band = (float*)ws;                        // rows*32 floats (2.1 MB)
    float* dinv = (float*)(ws + rows * 32 * 4);      // rows floats

    // 16384 waves: even = fill (2 full rows), odd = compute (2 rows)
    k_main<<<(int)(rows * 64 / 256), 256, 0, stream>>>(x, qmask, dia_len,
                                                       band, dinv, out);
    k_bw  <<<(int)(rows * 64 / 256), 256, 0, stream>>>(band, dinv, out);
}